// Round 7
// baseline (516.047 us; speedup 1.0000x reference)
//
#include <hip/hip_runtime.h>
#include <math.h>

#define V 50257
#define E 1024
#define HH 1024
#define LL 256

// d_out layout (floats): y | h_new(2*H) | c_new(2*H) | h_t_tilde(H) | a_t(L) | p_t
#define O_H  (V)
#define O_C  (V + 2*HH)
#define O_HT (V + 4*HH)
#define O_A  (V + 5*HH)
#define O_P  (V + 5*HH + LL)

// workspace layout (floats)
#define W_T    0       // tanh(Wp@h2)             [1024]
#define W_V    1024    // h2 @ Wbil               [1024] (atomics; zeroed in P0)
#define W_H1   2048    // aligned h1 copy         [1024]
#define W_H2   3072    // aligned h2 copy         [1024]
#define W_XT   4096    // aligned h_t_tilde copy  [1024]
#define W_BM   5120    // per-block max           [1024]
#define W_BS   6144    // per-block sum           [1024]
#define CTR_BYTE_OFF 28672   // 4 ints (zeroed by memset each call)

#define NW   4096      // waves in k_logits_bar (1024 blocks * 4)
#define MAXR 13        // ceil(V / NW)

__device__ __forceinline__ float sigmoidf_(float x) { return 1.f / (1.f + expf(-x)); }
__device__ __forceinline__ float dot4(float4 a, float4 b) {
    return a.x * b.x + a.y * b.y + a.z * b.z + a.w * b.w;
}

__device__ __forceinline__ float block_sum(float v, float* red) {
    int lane = threadIdx.x & 63, wv = threadIdx.x >> 6;
#pragma unroll
    for (int o = 32; o > 0; o >>= 1) v += __shfl_down(v, o, 64);
    __syncthreads();                 // protect red[] reuse across calls
    if (lane == 0) red[wv] = v;
    __syncthreads();
    return red[0] + red[1] + red[2] + red[3];
}

// device-wide barrier for all-resident grids.
// release: __syncthreads (drains vmcnt incl. atomics) + threadfence; signal via device-scope atomicAdd.
// acquire: atomic spin load (agent scope) + threadfence (invalidates L1 so post-barrier reads see L2).
__device__ __forceinline__ void gbar(int* ctr, int target) {
    __syncthreads();
    if (threadIdx.x == 0) {
        __threadfence();
        atomicAdd(ctr, 1);
        while (__hip_atomic_load(ctr, __ATOMIC_RELAXED, __HIP_MEMORY_SCOPE_AGENT) < target)
            __builtin_amdgcn_s_sleep(2);
        __threadfence();
    }
    __syncthreads();
}

// one LSTM unit: block-wide gate matvecs for rows u, u+H, u+2H, u+3H
__device__ __forceinline__ void lstm_unit(
    int u, const float* __restrict__ Wih, const float* __restrict__ Whh,
    const float* __restrict__ bih, const float* __restrict__ bhh,
    const float4* __restrict__ xa4, int na4, const float4* __restrict__ xb4, int nb4,
    const float* __restrict__ hprev, const float* __restrict__ cprev,
    float* __restrict__ hout, float* __restrict__ cout, float* __restrict__ hout2,
    float (*sm)[4]) {
    const int tid = threadIdx.x;
    const int K = (na4 + nb4) * 4, K4 = na4 + nb4;
    const float4* r0 = (const float4*)(Wih + (size_t)u * K);
    const float4* r1 = (const float4*)(Wih + (size_t)(u + HH) * K);
    const float4* r2 = (const float4*)(Wih + (size_t)(u + 2*HH) * K);
    const float4* r3 = (const float4*)(Wih + (size_t)(u + 3*HH) * K);
    float a0 = 0, a1 = 0, a2 = 0, a3 = 0;
    for (int j = tid; j < K4; j += 256) {
        float4 xv = (j < na4) ? xa4[j] : xb4[j - na4];
        a0 += dot4(r0[j], xv); a1 += dot4(r1[j], xv);
        a2 += dot4(r2[j], xv); a3 += dot4(r3[j], xv);
    }
    const float4* s0 = (const float4*)(Whh + (size_t)u * HH);
    const float4* s1 = (const float4*)(Whh + (size_t)(u + HH) * HH);
    const float4* s2 = (const float4*)(Whh + (size_t)(u + 2*HH) * HH);
    const float4* s3 = (const float4*)(Whh + (size_t)(u + 3*HH) * HH);
    const float4* hp4 = (const float4*)hprev;
    {
        int j = tid;                 // HH/4 == 256 == blockDim
        float4 hv = hp4[j];
        a0 += dot4(s0[j], hv); a1 += dot4(s1[j], hv);
        a2 += dot4(s2[j], hv); a3 += dot4(s3[j], hv);
    }
    int lane = tid & 63, wv = tid >> 6;
#pragma unroll
    for (int o = 32; o > 0; o >>= 1) {
        a0 += __shfl_down(a0, o, 64);
        a1 += __shfl_down(a1, o, 64);
        a2 += __shfl_down(a2, o, 64);
        a3 += __shfl_down(a3, o, 64);
    }
    __syncthreads();
    if (lane == 0) { sm[wv][0] = a0; sm[wv][1] = a1; sm[wv][2] = a2; sm[wv][3] = a3; }
    __syncthreads();
    if (tid == 0) {
        float gi = sm[0][0]+sm[1][0]+sm[2][0]+sm[3][0] + bih[u]      + bhh[u];
        float gf = sm[0][1]+sm[1][1]+sm[2][1]+sm[3][1] + bih[u+HH]   + bhh[u+HH];
        float gg = sm[0][2]+sm[1][2]+sm[2][2]+sm[3][2] + bih[u+2*HH] + bhh[u+2*HH];
        float go = sm[0][3]+sm[1][3]+sm[2][3]+sm[3][3] + bih[u+3*HH] + bhh[u+3*HH];
        float c = sigmoidf_(gf) * cprev[u] + sigmoidf_(gi) * tanhf(gg);
        float h = sigmoidf_(go) * tanhf(c);
        hout[u] = h; cout[u] = c; hout2[u] = h;
    }
}

// ---- front mega-kernel: LSTM0 | bar | LSTM1 | bar | Wp row + Wbil tiles | bar | attn+comb ----
__global__ __launch_bounds__(256, 4) void k_front(
    const int* __restrict__ tok, const float* __restrict__ emb, const float* __restrict__ htt,
    const float* __restrict__ h0, const float* __restrict__ c0,
    const float* __restrict__ Wih0, const float* __restrict__ Whh0,
    const float* __restrict__ bih0, const float* __restrict__ bhh0,
    const float* __restrict__ Wih1, const float* __restrict__ Whh1,
    const float* __restrict__ bih1, const float* __restrict__ bhh1,
    const float* __restrict__ Wp, const float* __restrict__ Wbil, const float* __restrict__ wdot,
    const float* __restrict__ hs, const float* __restrict__ Wcomb, const float* __restrict__ bcomb,
    float* __restrict__ h1o, float* __restrict__ c1o,
    float* __restrict__ h2o, float* __restrict__ c2o,
    float* __restrict__ htto, float* __restrict__ ato, float* __restrict__ pto,
    float* __restrict__ t_ws, float* __restrict__ v_ws,
    float* __restrict__ h1w, float* __restrict__ h2w, float* __restrict__ xtw,
    int* __restrict__ ctr) {
    const int u = blockIdx.x, tid = threadIdx.x;
    const int lane = tid & 63, wv = tid >> 6;
    __shared__ float red[4];
    __shared__ float sm[4][4];
    __shared__ float ssc[32];
    __shared__ float sa[LL];
    const int NB = gridDim.x;

    // P0: LSTM layer 0 (x = [emb[tok]; htt]) + zero v accumulator
    if (tid == 0) v_ws[u] = 0.f;
    lstm_unit(u, Wih0, Whh0, bih0, bhh0,
              (const float4*)(emb + (size_t)tok[0] * E), E/4,
              (const float4*)htt, HH/4,
              h0, c0, h1o, c1o, h1w, sm);
    gbar(ctr + 0, NB);

    // P1: LSTM layer 1 (x = h1)
    lstm_unit(u, Wih1, Whh1, bih1, bhh1,
              (const float4*)h1w, HH/4, (const float4*)h1w, 0,
              h0 + HH, c0 + HH, h2o, c2o, h2w, sm);
    gbar(ctr + 1, NB);

    // P2: t[u] = tanh(Wp_row_u . h2); blocks 0..31 also accumulate v = h2 @ Wbil
    {
        const float4* row = (const float4*)(Wp + (size_t)u * HH);
        const float4* h24 = (const float4*)h2w;
        float acc = dot4(row[tid], h24[tid]);
        float tot = block_sum(acc, red);
        if (tid == 0) t_ws[u] = tanhf(tot);
        if (u < 32) {
            int h0r = u * 32;
            const float4* W4 = (const float4*)Wbil;
            float4 a = make_float4(0.f, 0.f, 0.f, 0.f);
            for (int h = h0r; h < h0r + 32; ++h) {
                float hv = h2w[h];
                float4 w = W4[(size_t)h * 256 + tid];
                a.x += hv * w.x; a.y += hv * w.y; a.z += hv * w.z; a.w += hv * w.w;
            }
            atomicAdd(&v_ws[tid * 4 + 0], a.x);
            atomicAdd(&v_ws[tid * 4 + 1], a.y);
            atomicAdd(&v_ws[tid * 4 + 2], a.z);
            atomicAdd(&v_ws[tid * 4 + 3], a.w);
        }
    }
    gbar(ctr + 2, NB);

    // P3: p_t + window scores + softmax + in-register ctx + comb row u
    float p;
    {
        const float4* w4 = (const float4*)wdot;
        const float4* t4 = (const float4*)t_ws;
        float acc = dot4(w4[tid], t4[tid]);
        float tot = block_sum(acc, red);
        p = (float)LL * sigmoidf_(tot);
    }
    if (u == 0 && tid == 0) pto[0] = p;
    const int si = (int)rintf(p);
    const int lo = max(si - 10, 0), hi = min(si + 10, LL - 1);
    const int W = hi - lo + 1;          // <= 21
    const float4* v4 = (const float4*)v_ws;
    for (int l = lo + wv; l <= hi; l += 4) {
        const float4* row = (const float4*)(hs + (size_t)l * HH);
        float a = 0.f;
#pragma unroll
        for (int j = lane; j < 256; j += 64) a += dot4(row[j], v4[j]);
#pragma unroll
        for (int o = 32; o > 0; o >>= 1) a += __shfl_xor(a, o, 64);
        if (lane == 0) ssc[l - lo] = a;
    }
    __syncthreads();
    float M = -INFINITY;
    for (int i = 0; i < W; ++i) M = fmaxf(M, ssc[i]);
    float S = 0.f;
    for (int i = 0; i < W; ++i) S += expf(ssc[i] - M);
    {
        bool mask = (tid >= lo) && (tid <= hi);
        int wi = min(max(tid - lo, 0), 31);
        float e = mask ? expf(ssc[wi] - M) : 0.f;
        float d = (float)tid - p;
        float at = mask ? (e / S) * expf(d * d * 0.04f) : 0.f;  // exp(+d^2/(D/2)^2), faithful
        sa[tid] = at;
        if (u == 0) ato[tid] = at;
    }
    __syncthreads();
    const float4* hs4 = (const float4*)hs;
    float4 c = make_float4(0.f, 0.f, 0.f, 0.f);
    for (int l = lo; l <= hi; ++l) {
        float a = sa[l];
        float4 hv = hs4[(size_t)l * 256 + tid];
        c.x += a * hv.x; c.y += a * hv.y; c.z += a * hv.z; c.w += a * hv.w;
    }
    const float inv_win = 1.f / (float)W;
    c.x *= inv_win; c.y *= inv_win; c.z *= inv_win; c.w *= inv_win;
    {
        const float4* row = (const float4*)(Wcomb + (size_t)u * (2 * HH));
        const float4* h24 = (const float4*)h2w;
        float acc = dot4(row[tid], c) + dot4(row[256 + tid], h24[tid]);
        float tot = block_sum(acc, red);
        if (tid == 0) {
            float h = tanhf(tot + bcomb[u]);
            htto[u] = h; xtw[u] = h;
        }
    }
}

// ---- logits: wave w owns rows w, w+4096, ... (even per-CU); z in regs; bar; merge; write ----
__global__ __launch_bounds__(256, 4) void k_logits_bar(
    const float* __restrict__ Wout, const float* __restrict__ bout,
    const float* __restrict__ x, float* __restrict__ bmax, float* __restrict__ bsum,
    int* __restrict__ ctr, float* __restrict__ y) {
    const int tid = threadIdx.x, lane = tid & 63, wvi = tid >> 6;
    const int w = blockIdx.x * 4 + wvi;           // 0..4095
    const float4* x4 = (const float4*)x;
    float4 x0 = x4[lane], x1 = x4[lane + 64], x2 = x4[lane + 128], x3 = x4[lane + 192];
    float zreg[MAXR];
    float m = -INFINITY, s = 0.f;
#pragma unroll
    for (int i = 0; i < MAXR; ++i) {
        int r = w + i * NW;
        if (r < V) {
            const float4* row = (const float4*)(Wout + (size_t)r * 1024) + lane;
            float acc = dot4(row[0], x0) + dot4(row[64], x1)
                      + dot4(row[128], x2) + dot4(row[192], x3);
#pragma unroll
            for (int o = 32; o > 0; o >>= 1) acc += __shfl_xor(acc, o, 64);
            float zz = acc + bout[r];
            zreg[i] = zz;
            if (zz > m) { s *= expf(m - zz); m = zz; }
            s += expf(zz - m);
        }
    }
    __shared__ float wm[4], wsv[4];
    __shared__ float lzs;
    if (lane == 0) { wm[wvi] = m; wsv[wvi] = s; }
    __syncthreads();
    if (tid == 0) {
        float M = fmaxf(fmaxf(wm[0], wm[1]), fmaxf(wm[2], wm[3]));
        float S = 0.f;
#pragma unroll
        for (int wq = 0; wq < 4; ++wq) S += wsv[wq] * expf(wm[wq] - M);
        bmax[blockIdx.x] = M; bsum[blockIdx.x] = S;
    }
    gbar(ctr, gridDim.x);
    // redundant per-block merge of 1024 (max,sum) pairs -> logZ
    float mm = -INFINITY, ss = 0.f;
    for (int i = tid; i < 1024; i += 256) {
        float m2 = bmax[i], s2 = bsum[i];
        float MM = fmaxf(mm, m2);
        ss = ss * expf(mm - MM) + s2 * expf(m2 - MM);
        mm = MM;
    }
#pragma unroll
    for (int o = 32; o > 0; o >>= 1) {
        float m2 = __shfl_down(mm, o, 64), s2 = __shfl_down(ss, o, 64);
        float MM = fmaxf(mm, m2);
        ss = ss * expf(mm - MM) + s2 * expf(m2 - MM);
        mm = MM;
    }
    __syncthreads();
    if (lane == 0) { wm[wvi] = mm; wsv[wvi] = ss; }
    __syncthreads();
    if (tid == 0) {
        float MF = fmaxf(fmaxf(wm[0], wm[1]), fmaxf(wm[2], wm[3]));
        float SF = 0.f;
#pragma unroll
        for (int wq = 0; wq < 4; ++wq) SF += wsv[wq] * expf(wm[wq] - MF);
        lzs = MF + logf(SF);
    }
    __syncthreads();
    const float lz = lzs;
#pragma unroll
    for (int i = 0; i < MAXR; ++i) {
        int r = w + i * NW;
        if (r < V && lane == 0) y[r] = zreg[i] - lz;
    }
}

extern "C" void kernel_launch(void* const* d_in, const int* in_sizes, int n_in,
                              void* d_out, int out_size, void* d_ws, size_t ws_size,
                              hipStream_t stream) {
    const int*   tok   = (const int*)  d_in[0];
    const float* h0    = (const float*)d_in[1];
    const float* c0    = (const float*)d_in[2];
    const float* hs    = (const float*)d_in[3];
    const float* htt   = (const float*)d_in[4];
    const float* emb   = (const float*)d_in[5];
    const float* Wp    = (const float*)d_in[6];
    const float* wdot  = (const float*)d_in[7];
    const float* Wbil  = (const float*)d_in[8];
    const float* Wcomb = (const float*)d_in[9];
    const float* bcomb = (const float*)d_in[10];
    const float* Wih0  = (const float*)d_in[11];
    const float* Whh0  = (const float*)d_in[12];
    const float* bih0  = (const float*)d_in[13];
    const float* bhh0  = (const float*)d_in[14];
    const float* Wih1  = (const float*)d_in[15];
    const float* Whh1  = (const float*)d_in[16];
    const float* bih1  = (const float*)d_in[17];
    const float* bhh1  = (const float*)d_in[18];
    const float* Wout  = (const float*)d_in[19];
    const float* bout  = (const float*)d_in[20];

    float* out = (float*)d_out;
    float* ws  = (float*)d_ws;
    int*   ctr = (int*)((char*)d_ws + CTR_BYTE_OFF);

    float* h1o  = out + O_H;
    float* h2o  = out + O_H + HH;
    float* c1o  = out + O_C;
    float* c2o  = out + O_C + HH;
    float* htto = out + O_HT;
    float* ato  = out + O_A;
    float* pto  = out + O_P;

    hipMemsetAsync(ctr, 0, 16, stream);   // zero the 4 barrier counters each call

    hipLaunchKernelGGL(k_front, dim3(1024), dim3(256), 0, stream,
                       tok, emb, htt, h0, c0,
                       Wih0, Whh0, bih0, bhh0,
                       Wih1, Whh1, bih1, bhh1,
                       Wp, Wbil, wdot, hs, Wcomb, bcomb,
                       h1o, c1o, h2o, c2o, htto, ato, pto,
                       ws + W_T, ws + W_V, ws + W_H1, ws + W_H2, ws + W_XT,
                       ctr);
    hipLaunchKernelGGL(k_logits_bar, dim3(1024), dim3(256), 0, stream,
                       Wout, bout, ws + W_XT, ws + W_BM, ws + W_BS,
                       ctr + 3, out);
}

// Round 9
// 86.272 us; speedup vs baseline: 5.9816x; 5.9816x over previous
//
#include <hip/hip_runtime.h>
#include <math.h>

#define V 50257
#define E 1024
#define HH 1024
#define LL 256

// d_out layout (floats): y | h_new(2*H) | c_new(2*H) | h_t_tilde(H) | a_t(L) | p_t
#define O_H  (V)
#define O_C  (V + 2*HH)
#define O_HT (V + 4*HH)
#define O_A  (V + 5*HH)
#define O_P  (V + 5*HH + LL)

// workspace layout (floats) -- stays within the proven 56448-float footprint
#define W_T    0       // tanh(Wp@h2)            [1024]
#define W_V    1024    // h2 @ Wbil              [1024] (atomics; zeroed by k_lstm0)
#define W_H1   2048    // aligned h1 copy; reused as aligned h_t_tilde copy [1024]
#define W_H2   3072    // aligned h2 copy        [1024]
#define W_Z    4096    // logits                 [50257]
#define W_BM   54400   // per-block max          [1024]
#define W_BS   55424   // per-block sum          [1024]

#define NW   4096      // waves in k_logits (1024 blocks * 4)
#define MAXR 13        // ceil(V / NW)

__device__ __forceinline__ float sigmoidf_(float x) { return 1.f / (1.f + expf(-x)); }
__device__ __forceinline__ float dot4(float4 a, float4 b) {
    return a.x * b.x + a.y * b.y + a.z * b.z + a.w * b.w;
}

__device__ __forceinline__ float block_sum(float v, float* red) {
    int lane = threadIdx.x & 63, wv = threadIdx.x >> 6;
#pragma unroll
    for (int o = 32; o > 0; o >>= 1) v += __shfl_down(v, o, 64);
    __syncthreads();                 // protect red[] reuse across calls
    if (lane == 0) red[wv] = v;
    __syncthreads();
    return red[0] + red[1] + red[2] + red[3];
}

// ---- LSTM cell: block u computes gate rows u, u+H, u+2H, u+3H (float4 streams) ----
__global__ void k_lstm(const float* __restrict__ Wih, const float* __restrict__ Whh,
                       const float* __restrict__ bih, const float* __restrict__ bhh,
                       const float* __restrict__ xa_base, const int* __restrict__ tok,
                       const float* __restrict__ xb, int na, int nb,
                       const float* __restrict__ hprev, const float* __restrict__ cprev,
                       float* __restrict__ hout, float* __restrict__ cout,
                       float* __restrict__ hout2, float* __restrict__ zero_buf) {
    const int u = blockIdx.x;
    const int K = na + nb;
    const int K4 = K >> 2, na4 = na >> 2;
    if (zero_buf && threadIdx.x == 0) zero_buf[u] = 0.f;   // zero W_V for k_ptv atomics
    const float* xa = tok ? (xa_base + (size_t)tok[0] * na) : xa_base;
    const float4* xa4 = (const float4*)xa;
    const float4* xb4 = (const float4*)xb;
    const float4* r0 = (const float4*)(Wih + (size_t)u * K);
    const float4* r1 = (const float4*)(Wih + (size_t)(u + HH) * K);
    const float4* r2 = (const float4*)(Wih + (size_t)(u + 2*HH) * K);
    const float4* r3 = (const float4*)(Wih + (size_t)(u + 3*HH) * K);
    float a0 = 0, a1 = 0, a2 = 0, a3 = 0;
    for (int j = threadIdx.x; j < K4; j += 256) {
        float4 xv = (j < na4) ? xa4[j] : xb4[j - na4];
        a0 += dot4(r0[j], xv); a1 += dot4(r1[j], xv);
        a2 += dot4(r2[j], xv); a3 += dot4(r3[j], xv);
    }
    const float4* s0 = (const float4*)(Whh + (size_t)u * HH);
    const float4* s1 = (const float4*)(Whh + (size_t)(u + HH) * HH);
    const float4* s2 = (const float4*)(Whh + (size_t)(u + 2*HH) * HH);
    const float4* s3 = (const float4*)(Whh + (size_t)(u + 3*HH) * HH);
    const float4* hp4 = (const float4*)hprev;
    {
        int j = threadIdx.x;           // HH/4 == 256 == blockDim
        float4 hv = hp4[j];
        a0 += dot4(s0[j], hv); a1 += dot4(s1[j], hv);
        a2 += dot4(s2[j], hv); a3 += dot4(s3[j], hv);
    }
    int lane = threadIdx.x & 63, wv = threadIdx.x >> 6;
#pragma unroll
    for (int o = 32; o > 0; o >>= 1) {
        a0 += __shfl_down(a0, o, 64);
        a1 += __shfl_down(a1, o, 64);
        a2 += __shfl_down(a2, o, 64);
        a3 += __shfl_down(a3, o, 64);
    }
    __shared__ float sm[4][4];
    if (lane == 0) { sm[wv][0] = a0; sm[wv][1] = a1; sm[wv][2] = a2; sm[wv][3] = a3; }
    __syncthreads();
    if (threadIdx.x == 0) {
        float gi = sm[0][0]+sm[1][0]+sm[2][0]+sm[3][0] + bih[u]        + bhh[u];
        float gf = sm[0][1]+sm[1][1]+sm[2][1]+sm[3][1] + bih[u+HH]     + bhh[u+HH];
        float gg = sm[0][2]+sm[1][2]+sm[2][2]+sm[3][2] + bih[u+2*HH]   + bhh[u+2*HH];
        float go = sm[0][3]+sm[1][3]+sm[2][3]+sm[3][3] + bih[u+3*HH]   + bhh[u+3*HH];
        float c = sigmoidf_(gf) * cprev[u] + sigmoidf_(gi) * tanhf(gg);
        float h = sigmoidf_(go) * tanhf(c);
        hout[u] = h; cout[u] = c; hout2[u] = h;
    }
}

// ---- blocks [0,1024): t = tanh(Wp @ h2);  blocks [1024,1056): v += h2 @ Wbil tile ----
__global__ void k_ptv(const float* __restrict__ Wp, const float* __restrict__ Wbil,
                      const float* __restrict__ h2, float* __restrict__ t_out,
                      float* __restrict__ v_out) {
    __shared__ float red[4];
    if (blockIdx.x < HH) {
        int r = blockIdx.x;
        const float4* row = (const float4*)(Wp + (size_t)r * HH);
        const float4* h24 = (const float4*)h2;
        float acc = dot4(row[threadIdx.x], h24[threadIdx.x]);
        float tot = block_sum(acc, red);
        if (threadIdx.x == 0) t_out[r] = tanhf(tot);
    } else {
        int b = blockIdx.x - HH;        // 0..31, h-chunk of 32 rows
        int h0 = b * 32;
        int k4 = threadIdx.x;           // float4 column slot
        const float4* W4 = (const float4*)Wbil;
        float4 acc = make_float4(0.f, 0.f, 0.f, 0.f);
        for (int h = h0; h < h0 + 32; ++h) {
            float hv = h2[h];
            float4 w = W4[(size_t)h * 256 + k4];
            acc.x += hv * w.x; acc.y += hv * w.y;
            acc.z += hv * w.z; acc.w += hv * w.w;
        }
        atomicAdd(&v_out[k4 * 4 + 0], acc.x);
        atomicAdd(&v_out[k4 * 4 + 1], acc.y);
        atomicAdd(&v_out[k4 * 4 + 2], acc.z);
        atomicAdd(&v_out[k4 * 4 + 3], acc.w);
    }
}

// ---- comb with fully-absorbed attention: block u redundantly computes p, window
//      scores, softmax; thread tid computes ONLY its own ctx float4 slice; then
//      h_t_tilde[u] = tanh(Wcomb_row_u . [ctx/win ; h2] + bcomb[u]) ----
__global__ void k_combattn(const float* __restrict__ wdot, const float* __restrict__ t,
                           const float* __restrict__ v, const float* __restrict__ hs,
                           const float* __restrict__ h2, const float* __restrict__ Wcomb,
                           const float* __restrict__ bcomb,
                           float* __restrict__ outv, float* __restrict__ outv2,
                           float* __restrict__ ato, float* __restrict__ pto) {
    const int u = blockIdx.x, tid = threadIdx.x;
    const int lane = tid & 63, wv = tid >> 6;
    __shared__ float red[4];
    __shared__ float ssc[32];
    __shared__ float sa[LL];
    // p = L * sigmoid(wdot . t)   (identical in every block -> deterministic)
    float p;
    {
        const float4* w4 = (const float4*)wdot;
        const float4* t4 = (const float4*)t;
        float acc = dot4(w4[tid], t4[tid]);
        p = (float)LL * sigmoidf_(block_sum(acc, red));
    }
    if (u == 0 && tid == 0) pto[0] = p;
    const int si = (int)rintf(p);
    const int lo = max(si - 10, 0), hi = min(si + 10, LL - 1);
    const int W = hi - lo + 1;            // <= 21
    // window scores (L2-hot hs reads)
    const float4* v4 = (const float4*)v;
    for (int l = lo + wv; l <= hi; l += 4) {
        const float4* row = (const float4*)(hs + (size_t)l * HH);
        float a = 0.f;
#pragma unroll
        for (int j = lane; j < 256; j += 64) a += dot4(row[j], v4[j]);
#pragma unroll
        for (int o = 32; o > 0; o >>= 1) a += __shfl_xor(a, o, 64);
        if (lane == 0) ssc[l - lo] = a;
    }
    __syncthreads();
    float M = -INFINITY;
    for (int i = 0; i < W; ++i) M = fmaxf(M, ssc[i]);
    float S = 0.f;
    for (int i = 0; i < W; ++i) S += expf(ssc[i] - M);
    {
        bool mask = (tid >= lo) && (tid <= hi);
        int wi = min(max(tid - lo, 0), 31);
        float e = mask ? expf(ssc[wi] - M) : 0.f;
        float d = (float)tid - p;
        float at = mask ? (e / S) * expf(d * d * 0.04f) : 0.f;  // exp(+d^2/(D/2)^2), faithful
        sa[tid] = at;
        if (u == 0) ato[tid] = at;
    }
    __syncthreads();
    // own ctx slice + comb row
    const float4* hs4 = (const float4*)hs;
    float4 c = make_float4(0.f, 0.f, 0.f, 0.f);
    for (int l = lo; l <= hi; ++l) {
        float a = sa[l];
        float4 hv = hs4[(size_t)l * 256 + tid];
        c.x += a * hv.x; c.y += a * hv.y; c.z += a * hv.z; c.w += a * hv.w;
    }
    const float inv_win = 1.f / (float)W;
    c.x *= inv_win; c.y *= inv_win; c.z *= inv_win; c.w *= inv_win;
    {
        const float4* row = (const float4*)(Wcomb + (size_t)u * (2 * HH));
        const float4* h24 = (const float4*)h2;
        float acc = dot4(row[tid], c) + dot4(row[256 + tid], h24[tid]);
        float tot = block_sum(acc, red);
        if (tid == 0) {
            float h = tanhf(tot + bcomb[u]);
            outv[u] = h; outv2[u] = h;
        }
    }
}

// ---- logits: wave w owns rows w, w+4096, ... (balanced); x in VGPRs; online (max,sum) ----
__global__ void k_logits(const float* __restrict__ Wout, const float* __restrict__ bout,
                         const float* __restrict__ x, float* __restrict__ z,
                         float* __restrict__ bmax, float* __restrict__ bsum) {
    const int tid = threadIdx.x, lane = tid & 63, wvi = tid >> 6;
    const int w = blockIdx.x * 4 + wvi;           // 0..4095
    const float4* x4 = (const float4*)x;
    float4 x0 = x4[lane], x1 = x4[lane + 64], x2 = x4[lane + 128], x3 = x4[lane + 192];
    float m = -INFINITY, s = 0.f;
    for (int i = 0; i < MAXR; ++i) {
        int r = w + i * NW;
        if (r < V) {
            const float4* row = (const float4*)(Wout + (size_t)r * 1024) + lane;
            float acc = dot4(row[0], x0) + dot4(row[64], x1)
                      + dot4(row[128], x2) + dot4(row[192], x3);
#pragma unroll
            for (int o = 32; o > 0; o >>= 1) acc += __shfl_xor(acc, o, 64);
            float zz = acc + bout[r];
            if (lane == 0) z[r] = zz;
            if (zz > m) { s *= expf(m - zz); m = zz; }    // expf(-inf)=0 on first iter
            s += expf(zz - m);
        }
    }
    __shared__ float wm[4], wsv[4];
    if (lane == 0) { wm[wvi] = m; wsv[wvi] = s; }
    __syncthreads();
    if (tid == 0) {
        float M = fmaxf(fmaxf(wm[0], wm[1]), fmaxf(wm[2], wm[3]));
        float S = 0.f;
        if (M != -INFINITY) {
#pragma unroll
            for (int q = 0; q < 4; ++q)
                if (wm[q] != -INFINITY) S += wsv[q] * expf(wm[q] - M);
        }
        bmax[blockIdx.x] = M; bsum[blockIdx.x] = S;
    }
}

// ---- fused: per-block LSE merge over 1024 (max,sum) pairs then y = z - logZ ----
__global__ void k_sub(const float* __restrict__ z, const float* __restrict__ bmax,
                      const float* __restrict__ bsum, float* __restrict__ y) {
    int tid = threadIdx.x;
    float m = -INFINITY, s = 0.f;
    for (int i = tid; i < 1024; i += 256) {
        float m2 = bmax[i], s2 = bsum[i];
        float M = fmaxf(m, m2);
        if (M != -INFINITY) s = s * expf(m - M) + s2 * expf(m2 - M);
        m = M;
    }
    int lane = tid & 63, wv = tid >> 6;
#pragma unroll
    for (int o = 32; o > 0; o >>= 1) {
        float m2 = __shfl_down(m, o, 64), s2 = __shfl_down(s, o, 64);
        float M = fmaxf(m, m2);
        if (M != -INFINITY) s = s * expf(m - M) + s2 * expf(m2 - M);
        else s = 0.f;
        m = M;
    }
    __shared__ float wm[4], wsv[4];
    __shared__ float lzs;
    if (lane == 0) { wm[wv] = m; wsv[wv] = s; }
    __syncthreads();
    if (tid == 0) {
        float M = -INFINITY, S = 0.f;
#pragma unroll
        for (int q = 0; q < 4; ++q) {
            float M2 = fmaxf(M, wm[q]);
            if (M2 != -INFINITY) S = S * expf(M - M2) + wsv[q] * expf(wm[q] - M2);
            M = M2;
        }
        lzs = M + logf(S);
    }
    __syncthreads();
    float lz = lzs;
    int i = blockIdx.x * 256 + tid;
    if (i < V) y[i] = z[i] - lz;
}

extern "C" void kernel_launch(void* const* d_in, const int* in_sizes, int n_in,
                              void* d_out, int out_size, void* d_ws, size_t ws_size,
                              hipStream_t stream) {
    const int*   tok   = (const int*)  d_in[0];
    const float* h0    = (const float*)d_in[1];
    const float* c0    = (const float*)d_in[2];
    const float* hs    = (const float*)d_in[3];
    const float* htt   = (const float*)d_in[4];
    const float* emb   = (const float*)d_in[5];
    const float* Wp    = (const float*)d_in[6];
    const float* wdot  = (const float*)d_in[7];
    const float* Wbil  = (const float*)d_in[8];
    const float* Wcomb = (const float*)d_in[9];
    const float* bcomb = (const float*)d_in[10];
    const float* Wih0  = (const float*)d_in[11];
    const float* Whh0  = (const float*)d_in[12];
    const float* bih0  = (const float*)d_in[13];
    const float* bhh0  = (const float*)d_in[14];
    const float* Wih1  = (const float*)d_in[15];
    const float* Whh1  = (const float*)d_in[16];
    const float* bih1  = (const float*)d_in[17];
    const float* bhh1  = (const float*)d_in[18];
    const float* Wout  = (const float*)d_in[19];
    const float* bout  = (const float*)d_in[20];

    float* out = (float*)d_out;
    float* ws  = (float*)d_ws;

    float* h1o  = out + O_H;
    float* h2o  = out + O_H + HH;
    float* c1o  = out + O_C;
    float* c2o  = out + O_C + HH;
    float* htto = out + O_HT;
    float* ato  = out + O_A;
    float* pto  = out + O_P;

    hipLaunchKernelGGL(k_lstm, dim3(1024), dim3(256), 0, stream,
                       Wih0, Whh0, bih0, bhh0, emb, tok, htt, 1024, 1024,
                       h0, c0, h1o, c1o, ws + W_H1, ws + W_V);
    hipLaunchKernelGGL(k_lstm, dim3(1024), dim3(256), 0, stream,
                       Wih1, Whh1, bih1, bhh1, ws + W_H1, (const int*)nullptr,
                       ws + W_H1, 1024, 0,
                       h0 + HH, c0 + HH, h2o, c2o, ws + W_H2, (float*)nullptr);
    hipLaunchKernelGGL(k_ptv, dim3(1024 + 32), dim3(256), 0, stream,
                       Wp, Wbil, ws + W_H2, ws + W_T, ws + W_V);
    hipLaunchKernelGGL(k_combattn, dim3(1024), dim3(256), 0, stream,
                       wdot, ws + W_T, ws + W_V, hs, ws + W_H2, Wcomb, bcomb,
                       htto, ws + W_H1, ato, pto);   // W_H1 reused as aligned x copy
    hipLaunchKernelGGL(k_logits, dim3(1024), dim3(256), 0, stream,
                       Wout, bout, ws + W_H1, ws + W_Z, ws + W_BM, ws + W_BS);
    hipLaunchKernelGGL(k_sub, dim3((V + 255) / 256), dim3(256), 0, stream,
                       ws + W_Z, ws + W_BM, ws + W_BS, out);
}

// Round 10
// 84.924 us; speedup vs baseline: 6.0766x; 1.0159x over previous
//
#include <hip/hip_runtime.h>
#include <math.h>

#define V 50257
#define E 1024
#define HH 1024
#define LL 256

// d_out layout (floats): y | h_new(2*H) | c_new(2*H) | h_t_tilde(H) | a_t(L) | p_t
#define O_H  (V)
#define O_C  (V + 2*HH)
#define O_HT (V + 4*HH)
#define O_A  (V + 5*HH)
#define O_P  (V + 5*HH + LL)

// workspace layout (floats) -- identical to round-9 proven footprint
#define W_T    0       // tanh(Wp@h2)            [1024]
#define W_V    1024    // h2 @ Wbil              [1024] (atomics; zeroed by k_lstmA)
#define W_H1   2048    // aligned h1 copy; reused as aligned h_t_tilde copy [1024]
#define W_H2   3072    // aligned h2 copy        [1024]
#define W_Z    4096    // logits                 [50257]
#define W_BM   54400   // per-block max          [1024]
#define W_BS   55424   // per-block sum          [1024]
// LSTM1 gate partials (4 per u = 4096 floats) stashed in out[0..4096) -- y region,
// overwritten by k_sub at the end of every call.

#define NWL   8192     // waves in k_logits (1024 blocks * 8)
#define MAXR  7        // ceil(V / NWL)

__device__ __forceinline__ float sigmoidf_(float x) { return 1.f / (1.f + expf(-x)); }
__device__ __forceinline__ float dot4(float4 a, float4 b) {
    return a.x * b.x + a.y * b.y + a.z * b.z + a.w * b.w;
}

__device__ __forceinline__ float block_sum(float v, float* red) {
    int lane = threadIdx.x & 63, wv = threadIdx.x >> 6;
#pragma unroll
    for (int o = 32; o > 0; o >>= 1) v += __shfl_down(v, o, 64);
    __syncthreads();                 // protect red[] reuse across calls
    if (lane == 0) red[wv] = v;
    __syncthreads();
    return red[0] + red[1] + red[2] + red[3];
}

// ---- stage A (512 thr): LSTM0 full cell + Whh1@h0[1] gate partials ----
// block u: gate rows u, u+H, u+2H, u+3H. threads 0-255 also stream Whh0;
// threads 256-511 stream Whh1 (independent of h1) into separate accumulators.
__global__ __launch_bounds__(512) void k_lstmA(
    const float* __restrict__ Wih0, const float* __restrict__ Whh0,
    const float* __restrict__ Whh1,
    const float* __restrict__ bih0, const float* __restrict__ bhh0,
    const float* __restrict__ emb, const int* __restrict__ tok,
    const float* __restrict__ htt,
    const float* __restrict__ h0, const float* __restrict__ c0,
    float* __restrict__ h1o, float* __restrict__ c1o, float* __restrict__ h1w,
    float* __restrict__ p1, float* __restrict__ vzero) {
    const int u = blockIdx.x, tid = threadIdx.x;
    if (tid == 0) vzero[u] = 0.f;     // zero W_V for k_ptv atomics
    const float4* xa4 = (const float4*)(emb + (size_t)tok[0] * E);
    const float4* xb4 = (const float4*)htt;
    const float4* r0 = (const float4*)(Wih0 + (size_t)u * 2048);
    const float4* r1 = (const float4*)(Wih0 + (size_t)(u + HH) * 2048);
    const float4* r2 = (const float4*)(Wih0 + (size_t)(u + 2*HH) * 2048);
    const float4* r3 = (const float4*)(Wih0 + (size_t)(u + 3*HH) * 2048);
    float4 xv = (tid < 256) ? xa4[tid] : xb4[tid - 256];
    float a0 = dot4(r0[tid], xv), a1 = dot4(r1[tid], xv);
    float a2 = dot4(r2[tid], xv), a3 = dot4(r3[tid], xv);
    float b0 = 0.f, b1 = 0.f, b2 = 0.f, b3 = 0.f;
    if (tid < 256) {                  // wave-uniform branch (waves 0-3)
        const float4* s0 = (const float4*)(Whh0 + (size_t)u * HH);
        const float4* s1 = (const float4*)(Whh0 + (size_t)(u + HH) * HH);
        const float4* s2 = (const float4*)(Whh0 + (size_t)(u + 2*HH) * HH);
        const float4* s3 = (const float4*)(Whh0 + (size_t)(u + 3*HH) * HH);
        float4 hv = ((const float4*)h0)[tid];
        a0 += dot4(s0[tid], hv); a1 += dot4(s1[tid], hv);
        a2 += dot4(s2[tid], hv); a3 += dot4(s3[tid], hv);
    } else {                          // waves 4-7
        int j = tid - 256;
        const float4* t0 = (const float4*)(Whh1 + (size_t)u * HH);
        const float4* t1 = (const float4*)(Whh1 + (size_t)(u + HH) * HH);
        const float4* t2 = (const float4*)(Whh1 + (size_t)(u + 2*HH) * HH);
        const float4* t3 = (const float4*)(Whh1 + (size_t)(u + 3*HH) * HH);
        float4 gv = ((const float4*)(h0 + HH))[j];
        b0 = dot4(t0[j], gv); b1 = dot4(t1[j], gv);
        b2 = dot4(t2[j], gv); b3 = dot4(t3[j], gv);
    }
    const int lane = tid & 63, wv = tid >> 6;
#pragma unroll
    for (int o = 32; o > 0; o >>= 1) {
        a0 += __shfl_down(a0, o, 64); a1 += __shfl_down(a1, o, 64);
        a2 += __shfl_down(a2, o, 64); a3 += __shfl_down(a3, o, 64);
        b0 += __shfl_down(b0, o, 64); b1 += __shfl_down(b1, o, 64);
        b2 += __shfl_down(b2, o, 64); b3 += __shfl_down(b3, o, 64);
    }
    __shared__ float sma[8][4], smb[8][4];
    if (lane == 0) {
        sma[wv][0] = a0; sma[wv][1] = a1; sma[wv][2] = a2; sma[wv][3] = a3;
        smb[wv][0] = b0; smb[wv][1] = b1; smb[wv][2] = b2; smb[wv][3] = b3;
    }
    __syncthreads();
    if (tid == 0) {
        float g[4], p[4];
#pragma unroll
        for (int i = 0; i < 4; ++i) {
            float ga = 0.f, pb = 0.f;
#pragma unroll
            for (int w = 0; w < 8; ++w) { ga += sma[w][i]; pb += smb[w][i]; }
            g[i] = ga + bih0[u + i*HH] + bhh0[u + i*HH];
            p[i] = pb;
        }
        float c = sigmoidf_(g[1]) * c0[u] + sigmoidf_(g[0]) * tanhf(g[2]);
        float h = sigmoidf_(g[3]) * tanhf(c);
        h1o[u] = h; c1o[u] = c; h1w[u] = h;
        p1[u*4+0] = p[0]; p1[u*4+1] = p[1]; p1[u*4+2] = p[2]; p1[u*4+3] = p[3];
    }
}

// ---- stage B (256 thr): LSTM1 = Wih1@h1 + stashed Whh1 partials ----
__global__ void k_lstmB(
    const float* __restrict__ Wih1,
    const float* __restrict__ bih1, const float* __restrict__ bhh1,
    const float* __restrict__ h1w, const float* __restrict__ p1,
    const float* __restrict__ h0, const float* __restrict__ c0,
    float* __restrict__ h2o, float* __restrict__ c2o, float* __restrict__ h2w) {
    const int u = blockIdx.x, tid = threadIdx.x;
    const float4* r0 = (const float4*)(Wih1 + (size_t)u * HH);
    const float4* r1 = (const float4*)(Wih1 + (size_t)(u + HH) * HH);
    const float4* r2 = (const float4*)(Wih1 + (size_t)(u + 2*HH) * HH);
    const float4* r3 = (const float4*)(Wih1 + (size_t)(u + 3*HH) * HH);
    float4 hv = ((const float4*)h1w)[tid];
    float a0 = dot4(r0[tid], hv), a1 = dot4(r1[tid], hv);
    float a2 = dot4(r2[tid], hv), a3 = dot4(r3[tid], hv);
    const int lane = tid & 63, wv = tid >> 6;
#pragma unroll
    for (int o = 32; o > 0; o >>= 1) {
        a0 += __shfl_down(a0, o, 64); a1 += __shfl_down(a1, o, 64);
        a2 += __shfl_down(a2, o, 64); a3 += __shfl_down(a3, o, 64);
    }
    __shared__ float sm[4][4];
    if (lane == 0) { sm[wv][0] = a0; sm[wv][1] = a1; sm[wv][2] = a2; sm[wv][3] = a3; }
    __syncthreads();
    if (tid == 0) {
        float g[4];
#pragma unroll
        for (int i = 0; i < 4; ++i)
            g[i] = sm[0][i] + sm[1][i] + sm[2][i] + sm[3][i]
                 + p1[u*4+i] + bih1[u + i*HH] + bhh1[u + i*HH];
        float c = sigmoidf_(g[1]) * c0[HH + u] + sigmoidf_(g[0]) * tanhf(g[2]);
        float h = sigmoidf_(g[3]) * tanhf(c);
        h2o[u] = h; c2o[u] = c; h2w[u] = h;
    }
}

// ---- blocks [0,1024): t = tanh(Wp @ h2);  blocks [1024,1056): v += h2 @ Wbil tile ----
__global__ void k_ptv(const float* __restrict__ Wp, const float* __restrict__ Wbil,
                      const float* __restrict__ h2, float* __restrict__ t_out,
                      float* __restrict__ v_out) {
    __shared__ float red[4];
    if (blockIdx.x < HH) {
        int r = blockIdx.x;
        const float4* row = (const float4*)(Wp + (size_t)r * HH);
        const float4* h24 = (const float4*)h2;
        float acc = dot4(row[threadIdx.x], h24[threadIdx.x]);
        float tot = block_sum(acc, red);
        if (threadIdx.x == 0) t_out[r] = tanhf(tot);
    } else {
        int b = blockIdx.x - HH;        // 0..31, h-chunk of 32 rows
        int h0 = b * 32;
        int k4 = threadIdx.x;           // float4 column slot
        const float4* W4 = (const float4*)Wbil;
        float4 acc = make_float4(0.f, 0.f, 0.f, 0.f);
        for (int h = h0; h < h0 + 32; ++h) {
            float hv = h2[h];
            float4 w = W4[(size_t)h * 256 + k4];
            acc.x += hv * w.x; acc.y += hv * w.y;
            acc.z += hv * w.z; acc.w += hv * w.w;
        }
        atomicAdd(&v_out[k4 * 4 + 0], acc.x);
        atomicAdd(&v_out[k4 * 4 + 1], acc.y);
        atomicAdd(&v_out[k4 * 4 + 2], acc.z);
        atomicAdd(&v_out[k4 * 4 + 3], acc.w);
    }
}

// ---- comb with fully-absorbed attention (unchanged from round 9) ----
__global__ void k_combattn(const float* __restrict__ wdot, const float* __restrict__ t,
                           const float* __restrict__ v, const float* __restrict__ hs,
                           const float* __restrict__ h2, const float* __restrict__ Wcomb,
                           const float* __restrict__ bcomb,
                           float* __restrict__ outv, float* __restrict__ outv2,
                           float* __restrict__ ato, float* __restrict__ pto) {
    const int u = blockIdx.x, tid = threadIdx.x;
    const int lane = tid & 63, wv = tid >> 6;
    __shared__ float red[4];
    __shared__ float ssc[32];
    __shared__ float sa[LL];
    float p;
    {
        const float4* w4 = (const float4*)wdot;
        const float4* t4 = (const float4*)t;
        float acc = dot4(w4[tid], t4[tid]);
        p = (float)LL * sigmoidf_(block_sum(acc, red));
    }
    if (u == 0 && tid == 0) pto[0] = p;
    const int si = (int)rintf(p);
    const int lo = max(si - 10, 0), hi = min(si + 10, LL - 1);
    const int W = hi - lo + 1;            // <= 21
    const float4* v4 = (const float4*)v;
    for (int l = lo + wv; l <= hi; l += 4) {
        const float4* row = (const float4*)(hs + (size_t)l * HH);
        float a = 0.f;
#pragma unroll
        for (int j = lane; j < 256; j += 64) a += dot4(row[j], v4[j]);
#pragma unroll
        for (int o = 32; o > 0; o >>= 1) a += __shfl_xor(a, o, 64);
        if (lane == 0) ssc[l - lo] = a;
    }
    __syncthreads();
    float M = -INFINITY;
    for (int i = 0; i < W; ++i) M = fmaxf(M, ssc[i]);
    float S = 0.f;
    for (int i = 0; i < W; ++i) S += expf(ssc[i] - M);
    {
        bool mask = (tid >= lo) && (tid <= hi);
        int wi = min(max(tid - lo, 0), 31);
        float e = mask ? expf(ssc[wi] - M) : 0.f;
        float d = (float)tid - p;
        float at = mask ? (e / S) * expf(d * d * 0.04f) : 0.f;  // exp(+d^2/(D/2)^2), faithful
        sa[tid] = at;
        if (u == 0) ato[tid] = at;
    }
    __syncthreads();
    const float4* hs4 = (const float4*)hs;
    float4 c = make_float4(0.f, 0.f, 0.f, 0.f);
    for (int l = lo; l <= hi; ++l) {
        float a = sa[l];
        float4 hv = hs4[(size_t)l * 256 + tid];
        c.x += a * hv.x; c.y += a * hv.y; c.z += a * hv.z; c.w += a * hv.w;
    }
    const float inv_win = 1.f / (float)W;
    c.x *= inv_win; c.y *= inv_win; c.z *= inv_win; c.w *= inv_win;
    {
        const float4* row = (const float4*)(Wcomb + (size_t)u * (2 * HH));
        const float4* h24 = (const float4*)h2;
        float acc = dot4(row[tid], c) + dot4(row[256 + tid], h24[tid]);
        float tot = block_sum(acc, red);
        if (tid == 0) {
            float h = tanhf(tot + bcomb[u]);
            outv[u] = h; outv2[u] = h;
        }
    }
}

// ---- logits (512 thr): wave w owns rows w, w+8192, ...; x in VGPRs; online (max,sum) ----
__global__ __launch_bounds__(512) void k_logits(
    const float* __restrict__ Wout, const float* __restrict__ bout,
    const float* __restrict__ x, float* __restrict__ z,
    float* __restrict__ bmax, float* __restrict__ bsum) {
    const int tid = threadIdx.x, lane = tid & 63, wvi = tid >> 6;
    const int w = blockIdx.x * 8 + wvi;           // 0..8191
    const float4* x4 = (const float4*)x;
    float4 x0 = x4[lane], x1 = x4[lane + 64], x2 = x4[lane + 128], x3 = x4[lane + 192];
    float m = -INFINITY, s = 0.f;
    for (int i = 0; i < MAXR; ++i) {
        int r = w + i * NWL;
        if (r < V) {
            const float4* row = (const float4*)(Wout + (size_t)r * 1024) + lane;
            float acc = dot4(row[0], x0) + dot4(row[64], x1)
                      + dot4(row[128], x2) + dot4(row[192], x3);
#pragma unroll
            for (int o = 32; o > 0; o >>= 1) acc += __shfl_xor(acc, o, 64);
            float zz = acc + bout[r];
            if (lane == 0) z[r] = zz;
            if (zz > m) { s *= expf(m - zz); m = zz; }    // expf(-inf)=0 on first iter
            s += expf(zz - m);
        }
    }
    __shared__ float wm[8], wsv[8];
    if (lane == 0) { wm[wvi] = m; wsv[wvi] = s; }
    __syncthreads();
    if (tid == 0) {
        float M = -INFINITY;
#pragma unroll
        for (int q = 0; q < 8; ++q) M = fmaxf(M, wm[q]);
        float S = 0.f;
        if (M != -INFINITY) {
#pragma unroll
            for (int q = 0; q < 8; ++q)
                if (wm[q] != -INFINITY) S += wsv[q] * expf(wm[q] - M);
        }
        bmax[blockIdx.x] = M; bsum[blockIdx.x] = S;
    }
}

// ---- fused: per-block LSE merge over 1024 (max,sum) pairs then y = z - logZ ----
__global__ void k_sub(const float* __restrict__ z, const float* __restrict__ bmax,
                      const float* __restrict__ bsum, float* __restrict__ y) {
    int tid = threadIdx.x;
    float m = -INFINITY, s = 0.f;
    for (int i = tid; i < 1024; i += 256) {
        float m2 = bmax[i], s2 = bsum[i];
        float M = fmaxf(m, m2);
        if (M != -INFINITY) s = s * expf(m - M) + s2 * expf(m2 - M);
        m = M;
    }
    int lane = tid & 63, wv = tid >> 6;
#pragma unroll
    for (int o = 32; o > 0; o >>= 1) {
        float m2 = __shfl_down(m, o, 64), s2 = __shfl_down(s, o, 64);
        float M = fmaxf(m, m2);
        if (M != -INFINITY) s = s * expf(m - M) + s2 * expf(m2 - M);
        else s = 0.f;
        m = M;
    }
    __shared__ float wm[4], wsv[4];
    __shared__ float lzs;
    if (lane == 0) { wm[wv] = m; wsv[wv] = s; }
    __syncthreads();
    if (tid == 0) {
        float M = -INFINITY, S = 0.f;
#pragma unroll
        for (int q = 0; q < 4; ++q) {
            float M2 = fmaxf(M, wm[q]);
            if (M2 != -INFINITY) S = S * expf(M - M2) + wsv[q] * expf(wm[q] - M2);
            M = M2;
        }
        lzs = M + logf(S);
    }
    __syncthreads();
    float lz = lzs;
    int i = blockIdx.x * 256 + tid;
    if (i < V) y[i] = z[i] - lz;
}

extern "C" void kernel_launch(void* const* d_in, const int* in_sizes, int n_in,
                              void* d_out, int out_size, void* d_ws, size_t ws_size,
                              hipStream_t stream) {
    const int*   tok   = (const int*)  d_in[0];
    const float* h0    = (const float*)d_in[1];
    const float* c0    = (const float*)d_in[2];
    const float* hs    = (const float*)d_in[3];
    const float* htt   = (const float*)d_in[4];
    const float* emb   = (const float*)d_in[5];
    const float* Wp    = (const float*)d_in[6];
    const float* wdot  = (const float*)d_in[7];
    const float* Wbil  = (const float*)d_in[8];
    const float* Wcomb = (const float*)d_in[9];
    const float* bcomb = (const float*)d_in[10];
    const float* Wih0  = (const float*)d_in[11];
    const float* Whh0  = (const float*)d_in[12];
    const float* bih0  = (const float*)d_in[13];
    const float* bhh0  = (const float*)d_in[14];
    const float* Wih1  = (const float*)d_in[15];
    const float* Whh1  = (const float*)d_in[16];
    const float* bih1  = (const float*)d_in[17];
    const float* bhh1  = (const float*)d_in[18];
    const float* Wout  = (const float*)d_in[19];
    const float* bout  = (const float*)d_in[20];

    float* out = (float*)d_out;
    float* ws  = (float*)d_ws;

    float* h1o  = out + O_H;
    float* h2o  = out + O_H + HH;
    float* c1o  = out + O_C;
    float* c2o  = out + O_C + HH;
    float* htto = out + O_HT;
    float* ato  = out + O_A;
    float* pto  = out + O_P;
    float* p1   = out;            // y[0..4096) as scratch; overwritten by k_sub

    hipLaunchKernelGGL(k_lstmA, dim3(1024), dim3(512), 0, stream,
                       Wih0, Whh0, Whh1, bih0, bhh0, emb, tok, htt, h0, c0,
                       h1o, c1o, ws + W_H1, p1, ws + W_V);
    hipLaunchKernelGGL(k_lstmB, dim3(1024), dim3(256), 0, stream,
                       Wih1, bih1, bhh1, ws + W_H1, p1, h0, c0,
                       h2o, c2o, ws + W_H2);
    hipLaunchKernelGGL(k_ptv, dim3(1024 + 32), dim3(256), 0, stream,
                       Wp, Wbil, ws + W_H2, ws + W_T, ws + W_V);
    hipLaunchKernelGGL(k_combattn, dim3(1024), dim3(256), 0, stream,
                       wdot, ws + W_T, ws + W_V, hs, ws + W_H2, Wcomb, bcomb,
                       htto, ws + W_H1, ato, pto);   // W_H1 reused as aligned x copy
    hipLaunchKernelGGL(k_logits, dim3(1024), dim3(512), 0, stream,
                       Wout, bout, ws + W_H1, ws + W_Z, ws + W_BM, ws + W_BS);
    hipLaunchKernelGGL(k_sub, dim3((V + 255) / 256), dim3(256), 0, stream,
                       ws + W_Z, ws + W_BM, ws + W_BS, out);
}